// Round 7
// baseline (287.475 us; speedup 1.0000x reference)
//
#include <hip/hip_runtime.h>
#include <stdint.h>

// Problem constants
#define BB 4
#define LL 2048
#define DD 1024

typedef __attribute__((ext_vector_type(4))) float f32x4;
typedef __attribute__((ext_vector_type(8))) _Float16 f16x8;
typedef __attribute__((ext_vector_type(4))) unsigned short u16x4;
typedef __attribute__((ext_vector_type(8))) unsigned short u16x8;
typedef unsigned short u16;

// ---------- fp16 helper ----------
__device__ __forceinline__ u16 f2h(float x){
  return __builtin_bit_cast(u16, (_Float16)x);
}

// ---------- async global->LDS staging (16B/lane) ----------
__device__ __forceinline__ void gload16(const u16* g, u16* l){
  __builtin_amdgcn_global_load_lds((const __attribute__((address_space(1))) unsigned*)g,
                                   (__attribute__((address_space(3))) unsigned*)l,
                                   16, 0, 0);
}

// XCD-aware chunked block swizzle (requires nwg % 8 == 0; all our grids comply)
__device__ __forceinline__ int xcd_swz(int bx, int nwg){
  return (bx & 7) * (nwg >> 3) + (bx >> 3);
}

// stage a [128][64] fp16 tile, 8 waves, XOR-swizzled source, linear LDS dest
__device__ __forceinline__ void stage_tile8(u16* lds, const u16* src, int ld, int wave, int lane){
  const int r0 = lane >> 3;
  const int cs = (((lane & 7) ^ r0) << 3);
  #pragma unroll
  for (int j = 0; j < 2; ++j){
    const int rb = wave*16 + j*8;
    gload16(src + (size_t)(rb + r0)*ld + cs, lds + rb*64);
  }
}

// swizzled fragment read: logical (row, ko) lives at phys col ko ^ ((row&7)<<3)
__device__ __forceinline__ f16x8 frag_ld(const u16* t, int row, int ko){
  return __builtin_bit_cast(f16x8,
    *reinterpret_cast<const f32x4*>(t + row*64 + (ko ^ ((row & 7) << 3))));
}

// ---------- kernel: fused casts f1 -> f1f, W2 -> w2f ----------
__global__ void cast2_k(const float* __restrict__ f1, u16* __restrict__ f1f,
                        const float* __restrict__ W2, u16* __restrict__ w2f){
  const int n1 = (BB*LL*DD)/4, nw = (DD*DD)/4;
  const int stride = gridDim.x * blockDim.x;
  for (int i = blockIdx.x*blockDim.x + threadIdx.x; i < n1 + nw; i += stride){
    const float* s; u16* d; int k;
    if (i < n1){ s = f1; d = f1f; k = i; }
    else { s = W2; d = w2f; k = i - n1; }
    f32x4 v = reinterpret_cast<const f32x4*>(s)[k];
    u16x4 h;
    #pragma unroll
    for (int j = 0; j < 4; ++j) h[j] = f2h(v[j]);
    reinterpret_cast<u16x4*>(d)[k] = h;
  }
}

// ---------- kernel: cast + transpose. z<4: f2 batch z -> f2f,f2T. z==4: W1 -> w1f,w1T ----------
__global__ void castT_k(const float* __restrict__ f2, u16* __restrict__ f2f,
                        u16* __restrict__ f2T,
                        const float* __restrict__ W1, u16* __restrict__ w1f,
                        u16* __restrict__ w1T){
  __shared__ u16 t[32][33];
  const int z = blockIdx.z;
  const int d0 = blockIdx.x*32, l0 = blockIdx.y*32;
  const float* src; u16* d1; u16* d2; int nrow;
  if (z < 4){ src = f2 + (size_t)z*LL*DD; d1 = f2f + (size_t)z*LL*DD; d2 = f2T + (size_t)z*DD*LL; nrow = LL; }
  else      { src = W1; d1 = w1f; d2 = w1T; nrow = DD; }
  if (l0 >= nrow) return;
  const int x = threadIdx.x;
  const int ldT = (z < 4) ? LL : DD;
  for (int j = threadIdx.y; j < 32; j += 8){
    u16 h = f2h(src[(size_t)(l0+j)*DD + d0 + x]);
    d1[(size_t)(l0+j)*DD + d0 + x] = h;
    t[j][x] = h;
  }
  __syncthreads();
  for (int j = threadIdx.y; j < 32; j += 8)
    d2[(size_t)(d0+j)*ldT + l0 + x] = t[x][j];
}

// ---------- kernel: bz2[d] = b2[d] + sum_e W2[d][e]*b1[e]  (f32, wave per d) ----------
__global__ __launch_bounds__(512) void bz2_k(const float* __restrict__ W2,
                                             const float* __restrict__ b1,
                                             const float* __restrict__ b2,
                                             float* __restrict__ bz2){
  const int wave = threadIdx.x >> 6, lane = threadIdx.x & 63;
  const int d = blockIdx.x*8 + wave;
  float s = 0.f;
  #pragma unroll
  for (int k = 0; k < 16; ++k){
    const int e = lane + (k << 6);
    s += W2[(size_t)d*DD + e] * b1[e];
  }
  #pragma unroll
  for (int o = 32; o; o >>= 1) s += __shfl_xor(s, o, 64);
  if (lane == 0) bz2[d] = b2[d] + s;
}

// ---------- kernel: W12 = W2 @ W1 fp16 (A=w2f [i][e], B=w1T [j][e]), 128-tile ----------
__global__ __launch_bounds__(512,4) void w12_k(const u16* __restrict__ A_g,
                                               const u16* __restrict__ B_g,
                                               u16* __restrict__ Oh){
  __shared__ __align__(16) u16 As[128*64];
  __shared__ __align__(16) u16 Bs[128*64];
  const int bx = xcd_swz(blockIdx.x, gridDim.x);
  const int bm = bx >> 3, bn = bx & 7;
  const int tid = threadIdx.x, wave = tid>>6, lane = tid&63;
  const int wr = wave>>2, wc = wave&3;
  const u16* Ab = A_g + (size_t)(bm*128)*DD;
  const u16* Bb = B_g + (size_t)(bn*128)*DD;
  f32x4 acc[4][2];
  #pragma unroll
  for (int i=0;i<4;i++)
    #pragma unroll
    for (int j=0;j<2;j++) acc[i][j] = (f32x4){0.f,0.f,0.f,0.f};
  for (int k0 = 0; k0 < DD; k0 += 64){
    __syncthreads();
    stage_tile8(As, Ab + k0, DD, wave, lane);
    stage_tile8(Bs, Bb + k0, DD, wave, lane);
    __syncthreads();
    #pragma unroll
    for (int kk=0;kk<2;kk++){
      const int ko = kk*32 + ((lane>>4)<<3);
      f16x8 a[4], bb[2];
      #pragma unroll
      for (int mi=0;mi<4;mi++) a[mi]  = frag_ld(As, wr*64 + mi*16 + (lane&15), ko);
      #pragma unroll
      for (int ni=0;ni<2;ni++) bb[ni] = frag_ld(Bs, wc*32 + ni*16 + (lane&15), ko);
      #pragma unroll
      for (int mi=0;mi<4;mi++)
        #pragma unroll
        for (int ni=0;ni<2;ni++)
          acc[mi][ni] = __builtin_amdgcn_mfma_f32_16x16x32_f16(a[mi], bb[ni], acc[mi][ni], 0,0,0);
    }
  }
  #pragma unroll
  for (int mi=0;mi<4;mi++)
    #pragma unroll
    for (int ni=0;ni<2;ni++){
      const int r = bm*128 + wr*64 + mi*16 + ((lane>>4)<<2);
      const int c = bn*128 + wc*32 + ni*16 + (lane&15);
      #pragma unroll
      for (int j=0;j<4;j++)
        Oh[(size_t)(r+j)*DD + c] = f2h(acc[mi][ni][j]);
    }
}

// ---------- kernel: fused t1 + Zf. A=f1f, B1=w1f (t1 cols), B2=w12f (Z cols) ----------
// Outputs: t1f fp16 [r][c] (+b1), ZT fp16 transposed [b][d][m] (coalesced via LDS).
__global__ __launch_bounds__(512,4) void t1z_k(const u16* __restrict__ f1f,
                                               const u16* __restrict__ w1f,
                                               const u16* __restrict__ w12f,
                                               const float* __restrict__ b1,
                                               u16* __restrict__ t1f,
                                               u16* __restrict__ ZT){
  __shared__ __align__(16) u16 SH[3*128*64];       // As | B1s | B2s ; T aliases after
  u16* As  = SH;
  u16* B1s = SH + 8192;
  u16* B2s = SH + 16384;
  const int bx = xcd_swz(blockIdx.x, gridDim.x);
  const int bm = bx >> 3, bn = bx & 7;
  const int tid = threadIdx.x, wave = tid>>6, lane = tid&63;
  const int wr = wave>>2, wc = wave&3;
  const u16* Ab  = f1f  + (size_t)(bm*128)*DD;
  const u16* B1b = w1f  + (size_t)(bn*128)*DD;
  const u16* B2b = w12f + (size_t)(bn*128)*DD;
  f32x4 acc1[4][2], acc2[4][2];
  #pragma unroll
  for (int i=0;i<4;i++)
    #pragma unroll
    for (int j=0;j<2;j++){ acc1[i][j] = (f32x4){0.f,0.f,0.f,0.f}; acc2[i][j] = acc1[i][j]; }

  for (int k0 = 0; k0 < DD; k0 += 64){
    __syncthreads();
    stage_tile8(As,  Ab  + k0, DD, wave, lane);
    stage_tile8(B1s, B1b + k0, DD, wave, lane);
    stage_tile8(B2s, B2b + k0, DD, wave, lane);
    __syncthreads();
    #pragma unroll
    for (int kk=0;kk<2;kk++){
      const int ko = kk*32 + ((lane>>4)<<3);
      f16x8 a[4], b1v[2], b2v[2];
      #pragma unroll
      for (int mi=0;mi<4;mi++) a[mi]  = frag_ld(As, wr*64 + mi*16 + (lane&15), ko);
      #pragma unroll
      for (int ni=0;ni<2;ni++){
        b1v[ni] = frag_ld(B1s, wc*32 + ni*16 + (lane&15), ko);
        b2v[ni] = frag_ld(B2s, wc*32 + ni*16 + (lane&15), ko);
      }
      #pragma unroll
      for (int mi=0;mi<4;mi++)
        #pragma unroll
        for (int ni=0;ni<2;ni++){
          acc1[mi][ni] = __builtin_amdgcn_mfma_f32_16x16x32_f16(a[mi], b1v[ni], acc1[mi][ni], 0,0,0);
          acc2[mi][ni] = __builtin_amdgcn_mfma_f32_16x16x32_f16(a[mi], b2v[ni], acc2[mi][ni], 0,0,0);
        }
    }
  }
  // epilogue 1: t1f = acc1 + b1, direct
  #pragma unroll
  for (int mi=0;mi<4;mi++)
    #pragma unroll
    for (int ni=0;ni<2;ni++){
      const int r = bm*128 + wr*64 + mi*16 + ((lane>>4)<<2);
      const int c = bn*128 + wc*32 + ni*16 + (lane&15);
      const float bv = b1[c];
      #pragma unroll
      for (int j=0;j<4;j++)
        t1f[(size_t)(r+j)*DD + c] = f2h(acc1[mi][ni][j] + bv);
    }
  // epilogue 2: ZT via LDS transpose staging (T aliases SH)
  __syncthreads();
  u16* T = SH;                                  // [128][132]
  #pragma unroll
  for (int mi=0;mi<4;mi++)
    #pragma unroll
    for (int ni=0;ni<2;ni++){
      const int r = wr*64 + mi*16 + ((lane>>4)<<2);
      const int c = wc*32 + ni*16 + (lane&15);
      #pragma unroll
      for (int j=0;j<4;j++)
        T[(r+j)*132 + c] = f2h(acc2[mi][ni][j]);
    }
  __syncthreads();
  const int b2i = bm >> 4;
  const int mb  = (bm*128) & 2047;
  const int d   = tid >> 2, m0 = (tid & 3) << 5;
  u16* dst = ZT + ((size_t)b2i*DD + bn*128 + d)*LL + mb + m0;
  #pragma unroll
  for (int g = 0; g < 4; ++g){
    u16x8 v;
    #pragma unroll
    for (int e = 0; e < 8; ++e) v[e] = T[(m0 + g*8 + e)*132 + d];
    *reinterpret_cast<u16x8*>(dst + g*8) = v;
  }
}

// ================= 8-phase 256x256 fp16 GEMM (sim) =================
__global__ __launch_bounds__(512,2) void gemm8p_k(
    const u16* __restrict__ A_g, long long sAb, int lda,
    const u16* __restrict__ B_g, long long sBb, int ldb,
    float* __restrict__ C, long long sCb, int ldc, int NT){
  __shared__ __align__(16) u16 As[4][128*64];
  __shared__ __align__(16) u16 Bs[4][128*64];
  const int b = blockIdx.y;
  const int bx = xcd_swz(blockIdx.x, gridDim.x);
  const int bm = bx >> 3, bn = bx & 7;
  const int tid = threadIdx.x, wave = tid>>6, lane = tid&63;
  const int wm = wave & 1, wn = wave >> 1;
  const int r0 = lane >> 3, cs = (((lane&7) ^ r0) << 3);
  const int rb0 = wave*16;
  const u16* Ab = A_g + (size_t)b*sAb + (size_t)(bm*256)*lda;
  const u16* Bb = B_g + (size_t)b*sBb + (size_t)(bn*256)*ldb;

  f32x4 acc[2][2][4][2];
  #pragma unroll
  for (int i=0;i<2;i++)
    #pragma unroll
    for (int j=0;j<2;j++)
      #pragma unroll
      for (int m=0;m<4;m++)
        #pragma unroll
        for (int n=0;n<2;n++) acc[i][j][m][n] = (f32x4){0.f,0.f,0.f,0.f};

  auto stA = [&](int tt, int h){
    const u16* s = Ab + (size_t)(h*128 + rb0 + r0)*lda + (size_t)tt*64 + cs;
    u16* d = &As[((tt&1)<<1)+h][rb0*64];
    gload16(s, d);
    gload16(s + (size_t)8*lda, d + 8*64);
  };
  auto stB = [&](int tt, int h){
    const u16* s = Bb + (size_t)(h*128 + rb0 + r0)*ldb + (size_t)tt*64 + cs;
    u16* d = &Bs[((tt&1)<<1)+h][rb0*64];
    gload16(s, d);
    gload16(s + (size_t)8*ldb, d + 8*64);
  };

  stA(0,0); stB(0,0); stA(0,1); stB(0,1);
  stA(1,0); stB(1,0);
  asm volatile("s_waitcnt vmcnt(4)" ::: "memory");
  __builtin_amdgcn_s_barrier();

  for (int t = 0; t < NT; ++t){
    #pragma unroll
    for (int p = 0; p < 4; ++p){
      const u16* Ah = As[((t&1)<<1) + (p>>1)];
      const u16* Bh = Bs[((t&1)<<1) + (p&1)];
      f16x8 af[4][2], bf[2][2];
      #pragma unroll
      for (int mi=0;mi<4;mi++)
        #pragma unroll
        for (int ks=0;ks<2;ks++)
          af[mi][ks] = frag_ld(Ah, wm*64 + mi*16 + (lane&15), ks*32 + ((lane>>4)<<3));
      #pragma unroll
      for (int ni=0;ni<2;ni++)
        #pragma unroll
        for (int ks=0;ks<2;ks++)
          bf[ni][ks] = frag_ld(Bh, wn*32 + ni*16 + (lane&15), ks*32 + ((lane>>4)<<3));
      if (p == 0){ if (t+1 < NT) stA(t+1, 1); }
      else if (p == 1){ if (t+1 < NT) stB(t+1, 1); }
      else if (p == 2){ if (t+2 < NT) stA(t+2, 0); }
      else {
        if (t+2 < NT){ stB(t+2, 0); asm volatile("s_waitcnt vmcnt(4)" ::: "memory"); }
        else         {              asm volatile("s_waitcnt vmcnt(0)" ::: "memory"); }
      }
      __builtin_amdgcn_s_barrier();
      asm volatile("s_waitcnt lgkmcnt(0)" ::: "memory");
      __builtin_amdgcn_sched_barrier(0);
      __builtin_amdgcn_s_setprio(1);
      #pragma unroll
      for (int mi=0;mi<4;mi++)
        #pragma unroll
        for (int ni=0;ni<2;ni++)
          #pragma unroll
          for (int ks=0;ks<2;ks++)
            acc[p>>1][p&1][mi][ni] = __builtin_amdgcn_mfma_f32_16x16x32_f16(
                af[mi][ks], bf[ni][ks], acc[p>>1][p&1][mi][ni], 0,0,0);
      __builtin_amdgcn_s_setprio(0);
      __builtin_amdgcn_sched_barrier(0);
      __builtin_amdgcn_s_barrier();
    }
  }

  #pragma unroll
  for (int qm=0;qm<2;qm++)
    #pragma unroll
    for (int qn=0;qn<2;qn++)
      #pragma unroll
      for (int mi=0;mi<4;mi++)
        #pragma unroll
        for (int ni=0;ni<2;ni++){
          const int r = bm*256 + qm*128 + wm*64 + mi*16 + ((lane>>4)<<2);
          const int c = bn*256 + qn*128 + wn*32 + ni*16 + (lane&15);
          float* Cb = C + (size_t)b*sCb;
          #pragma unroll
          for (int j=0;j<4;j++)
            Cb[(size_t)(r+j)*ldc + c] = acc[qm][qn][mi][ni][j];
        }
}

// ---------- kernel: row softmax f32->fp16 in place ----------
__global__ __launch_bounds__(256) void softmax_k(float* __restrict__ sim){
  const int row = blockIdx.x;
  float* p = sim + (size_t)row * LL;
  const int tid = threadIdx.x, wave = tid>>6, lane = tid&63;
  f32x4 x0 = reinterpret_cast<const f32x4*>(p)[tid];
  f32x4 x1 = reinterpret_cast<const f32x4*>(p)[tid + 256];
  float mx = fmaxf(fmaxf(fmaxf(x0[0],x0[1]), fmaxf(x0[2],x0[3])),
                   fmaxf(fmaxf(x1[0],x1[1]), fmaxf(x1[2],x1[3])));
  #pragma unroll
  for (int o = 32; o; o >>= 1) mx = fmaxf(mx, __shfl_xor(mx, o, 64));
  __shared__ float red[8];
  if (lane == 0) red[wave] = mx;
  __syncthreads();
  mx = fmaxf(fmaxf(red[0], red[1]), fmaxf(red[2], red[3]));
  float e0[4], e1[4], s = 0.f;
  #pragma unroll
  for (int j=0;j<4;j++){ e0[j] = __expf(x0[j]-mx); s += e0[j]; }
  #pragma unroll
  for (int j=0;j<4;j++){ e1[j] = __expf(x1[j]-mx); s += e1[j]; }
  #pragma unroll
  for (int o = 32; o; o >>= 1) s += __shfl_xor(s, o, 64);
  if (lane == 0) red[4+wave] = s;
  __syncthreads();
  s = (red[4]+red[5]) + (red[6]+red[7]);
  const float inv = 1.0f / s;
  u16* ob = reinterpret_cast<u16*>(p);
  u16x4 w0, w1;
  #pragma unroll
  for (int j=0;j<4;j++){ w0[j] = f2h(e0[j]*inv); w1[j] = f2h(e1[j]*inv); }
  reinterpret_cast<u16x4*>(ob)[tid]       = w0;
  reinterpret_cast<u16x4*>(ob)[tid + 256] = w1;
}

// ---------- kernel: fused dual-B PV — stage attn once, out1 & out2 together ----------
// grid (128, BB): bm = bx>>3 (16 row-tiles), dn = bx&7 (8 col-tiles of 128).
// A = attn fp16 (ld 4096), B1 = f2T, B2 = ZT (both [b][1024][2048], ld LL). K=2048.
__global__ __launch_bounds__(512,4) void pv2_k(const u16* __restrict__ attn,
                                               const u16* __restrict__ f2T,
                                               const u16* __restrict__ ZT,
                                               float* __restrict__ out1,
                                               float* __restrict__ out2,
                                               const float* __restrict__ bz2){
  __shared__ __align__(16) u16 As[128*64];
  __shared__ __align__(16) u16 B1s[128*64];
  __shared__ __align__(16) u16 B2s[128*64];
  const int b = blockIdx.y;
  const int bx = xcd_swz(blockIdx.x, gridDim.x);
  const int bm = bx >> 3, dn = bx & 7;
  const int tid = threadIdx.x, wave = tid>>6, lane = tid&63;
  const int wr = wave>>2, wc = wave&3;
  const u16* Ab  = attn + (size_t)b*LL*4096 + (size_t)(bm*128)*4096;
  const u16* B1b = f2T + (size_t)b*DD*LL + (size_t)(dn*128)*LL;
  const u16* B2b = ZT  + (size_t)b*DD*LL + (size_t)(dn*128)*LL;
  f32x4 acc1[4][2], acc2[4][2];
  #pragma unroll
  for (int i=0;i<4;i++)
    #pragma unroll
    for (int j=0;j<2;j++){ acc1[i][j] = (f32x4){0.f,0.f,0.f,0.f}; acc2[i][j] = acc1[i][j]; }

  for (int k0 = 0; k0 < LL; k0 += 64){
    __syncthreads();
    stage_tile8(As,  Ab  + k0, 4096, wave, lane);
    stage_tile8(B1s, B1b + k0, LL, wave, lane);
    stage_tile8(B2s, B2b + k0, LL, wave, lane);
    __syncthreads();
    #pragma unroll
    for (int kk=0;kk<2;kk++){
      const int ko = kk*32 + ((lane>>4)<<3);
      f16x8 a[4], b1v[2], b2v[2];
      #pragma unroll
      for (int mi=0;mi<4;mi++) a[mi]  = frag_ld(As, wr*64 + mi*16 + (lane&15), ko);
      #pragma unroll
      for (int ni=0;ni<2;ni++){
        b1v[ni] = frag_ld(B1s, wc*32 + ni*16 + (lane&15), ko);
        b2v[ni] = frag_ld(B2s, wc*32 + ni*16 + (lane&15), ko);
      }
      #pragma unroll
      for (int mi=0;mi<4;mi++)
        #pragma unroll
        for (int ni=0;ni<2;ni++){
          acc1[mi][ni] = __builtin_amdgcn_mfma_f32_16x16x32_f16(a[mi], b1v[ni], acc1[mi][ni], 0,0,0);
          acc2[mi][ni] = __builtin_amdgcn_mfma_f32_16x16x32_f16(a[mi], b2v[ni], acc2[mi][ni], 0,0,0);
        }
    }
  }
  float* O1 = out1 + (size_t)b*LL*DD;
  float* O2 = out2 + (size_t)b*LL*DD;
  #pragma unroll
  for (int mi=0;mi<4;mi++)
    #pragma unroll
    for (int ni=0;ni<2;ni++){
      const int r = bm*128 + wr*64 + mi*16 + ((lane>>4)<<2);
      const int c = dn*128 + wc*32 + ni*16 + (lane&15);
      const float bv = bz2[c];
      #pragma unroll
      for (int j=0;j<4;j++){
        O1[(size_t)(r+j)*DD + c] = acc1[mi][ni][j];
        O2[(size_t)(r+j)*DD + c] = acc2[mi][ni][j] + bv;
      }
    }
}

// ---------- host launch ----------
extern "C" void kernel_launch(void* const* d_in, const int* in_sizes, int n_in,
                              void* d_out, int out_size, void* d_ws, size_t ws_size,
                              hipStream_t stream) {
  const float* f1 = (const float*)d_in[0];
  const float* f2 = (const float*)d_in[1];
  const float* W1 = (const float*)d_in[2];
  const float* b1 = (const float*)d_in[3];
  const float* W2 = (const float*)d_in[4];
  const float* b2 = (const float*)d_in[5];
  float* out1 = (float*)d_out;
  float* out2 = out1 + (size_t)BB*LL*DD;

  // workspace layout (bytes); peak 128 MB + 4 KB
  char* ws = (char*)d_ws;
  u16* t1f = (u16*)(ws + 0);              // 16 MiB  fp16 t1
  u16* ZT  = (u16*)(ws + 16777216);       // 16 MiB  fp16 Z^T [b][1024][2048]
  u16* f2f = (u16*)(ws + 33554432);       // 16 MiB  fp16 f2
  u16* f2T = (u16*)(ws + 50331648);       // 16 MiB  fp16 f2^T
  float* sim = (float*)(ws + 67108864);   // 64 MiB f32; attn fp16 in place
  // short-lived buffers alias the sim region (all dead before the sim GEMM):
  u16* f1f  = (u16*)(ws + 67108864);                // 16 MiB
  u16* w1T  = (u16*)(ws + 67108864 + 16777216);     // 2 MiB
  u16* w12f = (u16*)(ws + 67108864 + 18874368);     // 2 MiB
  u16* w2f  = (u16*)(ws + 67108864 + 20971520);     // 2 MiB
  u16* w1f  = (u16*)(ws + 67108864 + 23068672);     // 2 MiB
  float* bz2 = (float*)(ws + 134217728);  // 4 KiB (persists through pv2)

  // 1. casts: f2 (+T) and W1 (+T); f1 and W2 flat
  castT_k<<<dim3(32, 64, 5), dim3(32, 8), 0, stream>>>(f2, f2f, f2T, W1, w1f, w1T);
  cast2_k<<<4096, 256, 0, stream>>>(f1, f1f, W2, w2f);
  // 2. bz2 = b2 + W2 @ b1 (f32, from original inputs)
  bz2_k<<<128, 512, 0, stream>>>(W2, b1, b2, bz2);
  // 3. W12 = W2 @ W1 (fp16)
  w12_k<<<64, 512, 0, stream>>>(w2f, w1T, w12f);
  // 4. fused: t1 = f1@W1^T + b1 -> t1f ; Zf = f1@W12^T -> ZT (transposed)
  t1z_k<<<512, 512, 0, stream>>>(f1f, w1f, w12f, b1, t1f, ZT);
  // 5. sim[b] = t1[b] @ f2[b]^T — 8-phase 256x256, NT=16
  gemm8p_k<<<dim3(64, BB), 512, 0, stream>>>(t1f, (long long)LL*DD, DD,
                                             f2f, (long long)LL*DD, DD,
                                             sim, (long long)LL*LL, LL, 16);
  // 6. softmax rows, attn fp16 in place (row stride 4096 elems)
  softmax_k<<<BB*LL, 256, 0, stream>>>(sim);
  // 7. fused dual-B PV: out1 = attn@f2 ; out2 = attn@Zf + bz2
  pv2_k<<<dim3(128, BB), 512, 0, stream>>>((const u16*)sim, f2T, ZT,
                                           out1, out2, bz2);
}